// Round 1
// baseline (325.774 us; speedup 1.0000x reference)
//
#include <hip/hip_runtime.h>
#include <stdint.h>

#define T_ROWS 8192
#define IN_F 4096
#define OUT_F 4096

using i32x4 = __attribute__((ext_vector_type(4))) int;

#define GLOBAL_AS __attribute__((address_space(1)))
#define LDS_AS __attribute__((address_space(3)))

static __device__ __forceinline__ void load_lds16(const void* g, void* l) {
    __builtin_amdgcn_global_load_lds((const GLOBAL_AS uint32_t*)g,
                                     (LDS_AS uint32_t*)l, 16, 0, 0);
}

// ---------------- Kernel 1: per-row absmax int8 quantization ----------------
// One block (256 threads) per row of 4096 floats. 16 floats/thread.
__global__ __launch_bounds__(256) void quant_kernel(const float* __restrict__ x,
                                                    int8_t* __restrict__ xq,
                                                    float* __restrict__ scales) {
    const int row = blockIdx.x;
    const float* xr = x + (size_t)row * IN_F;
    const float4* xr4 = (const float4*)xr;

    float4 v[4];
    float amax = 0.0f;
#pragma unroll
    for (int i = 0; i < 4; ++i) {
        v[i] = xr4[threadIdx.x + 256 * i];
        amax = fmaxf(amax, fmaxf(fmaxf(fabsf(v[i].x), fabsf(v[i].y)),
                                 fmaxf(fabsf(v[i].z), fabsf(v[i].w))));
    }
    // wave64 reduce
#pragma unroll
    for (int off = 32; off; off >>= 1)
        amax = fmaxf(amax, __shfl_xor(amax, off, 64));
    __shared__ float smax[4];
    if ((threadIdx.x & 63) == 0) smax[threadIdx.x >> 6] = amax;
    __syncthreads();
    amax = fmaxf(fmaxf(smax[0], smax[1]), fmaxf(smax[2], smax[3]));

    const float act_scale = fmaxf(amax, 1e-10f) / 127.0f;
    if (threadIdx.x == 0) scales[row] = act_scale;

    int* xqr = (int*)(xq + (size_t)row * IN_F);
#pragma unroll
    for (int i = 0; i < 4; ++i) {
        // round(x/s) then clip, matching the reference (RNE = jnp.round)
        int q0 = (int)fminf(fmaxf(rintf(v[i].x / act_scale), -127.0f), 127.0f);
        int q1 = (int)fminf(fmaxf(rintf(v[i].y / act_scale), -127.0f), 127.0f);
        int q2 = (int)fminf(fmaxf(rintf(v[i].z / act_scale), -127.0f), 127.0f);
        int q3 = (int)fminf(fmaxf(rintf(v[i].w / act_scale), -127.0f), 127.0f);
        int packed = (q0 & 0xff) | ((q1 & 0xff) << 8) | ((q2 & 0xff) << 16) | (q3 << 24);
        xqr[threadIdx.x + 256 * i] = packed;
    }
}

// ---------------- Kernel 2: ternary f32 weights -> int8 ----------------
__global__ __launch_bounds__(256) void wq_kernel(const float* __restrict__ w,
                                                 int8_t* __restrict__ w8) {
    const float4* w4 = (const float4*)w;
    int* o4 = (int*)w8;
    size_t base = (size_t)blockIdx.x * 1024 + threadIdx.x;
#pragma unroll
    for (int i = 0; i < 4; ++i) {
        size_t idx = base + 256 * i;
        float4 v = w4[idx];
        int q0 = (int)v.x, q1 = (int)v.y, q2 = (int)v.z, q3 = (int)v.w;
        o4[idx] = (q0 & 0xff) | ((q1 & 0xff) << 8) | ((q2 & 0xff) << 16) | (q3 << 24);
    }
}

// ---------------- Kernel 3: int8 MFMA GEMM ----------------
// C[t][o] = sum_k xq[t][k] * w8[o][k]  (NT layout: both row-major, K contiguous)
// Tile 128x128, BK=64, 256 threads = 4 waves in 2x2.
// LDS layout: [kchunk 0..3][row 0..127][16 bytes] so ds_read_b128 is stride-16B
// across the 16 lanes of a fragment group (conflict-free; 2-way is free).
__global__ __launch_bounds__(256) void gemm_kernel(const int8_t* __restrict__ xq,
                                                   const int8_t* __restrict__ w8,
                                                   const float* __restrict__ scales,
                                                   const float* __restrict__ bias,
                                                   const float* __restrict__ wscale_p,
                                                   float* __restrict__ out) {
    __shared__ __align__(16) int8_t As[4 * 128 * 16];  // 8 KiB
    __shared__ __align__(16) int8_t Bs[4 * 128 * 16];  // 8 KiB

    const int tid = threadIdx.x;
    const int lane = tid & 63;
    const int wid = tid >> 6;
    const int wr = wid >> 1;        // wave row 0..1 (64 rows each)
    const int wc = wid & 1;         // wave col 0..1 (64 cols each)
    const int brow = blockIdx.y * 128;
    const int bcol = blockIdx.x * 128;

    // staging: thread handles flat slots t in {tid, tid+256}; slot t covers
    // LDS bytes [t*16, t*16+16) = chunk (t>>7), row (t&127).
    const int t0 = tid, t1 = tid + 256;
    const int8_t* gA0 = xq + (size_t)(brow + (t0 & 127)) * IN_F + (t0 >> 7) * 16;
    const int8_t* gA1 = xq + (size_t)(brow + (t1 & 127)) * IN_F + (t1 >> 7) * 16;
    const int8_t* gB0 = w8 + (size_t)(bcol + (t0 & 127)) * IN_F + (t0 >> 7) * 16;
    const int8_t* gB1 = w8 + (size_t)(bcol + (t1 & 127)) * IN_F + (t1 >> 7) * 16;
    int8_t* lA0 = As + t0 * 16;
    int8_t* lA1 = As + t1 * 16;
    int8_t* lB0 = Bs + t0 * 16;
    int8_t* lB1 = Bs + t1 * 16;

    // fragment read pointers: lane l -> kchunk = l>>4, 16-row index = l&15
    const int chunk = lane >> 4;
    const int r16 = lane & 15;
    const int8_t* fA[4];
    const int8_t* fB[4];
#pragma unroll
    for (int m = 0; m < 4; ++m)
        fA[m] = As + (chunk * 128 + wr * 64 + m * 16 + r16) * 16;
#pragma unroll
    for (int n = 0; n < 4; ++n)
        fB[n] = Bs + (chunk * 128 + wc * 64 + n * 16 + r16) * 16;

    i32x4 acc[4][4] = {};

    for (int kt = 0; kt < IN_F / 64; ++kt) {
        const int k0 = kt * 64;
        load_lds16(gA0 + k0, lA0);
        load_lds16(gA1 + k0, lA1);
        load_lds16(gB0 + k0, lB0);
        load_lds16(gB1 + k0, lB1);
        __syncthreads();

        i32x4 a[4], b[4];
#pragma unroll
        for (int m = 0; m < 4; ++m) a[m] = *(const i32x4*)fA[m];
#pragma unroll
        for (int n = 0; n < 4; ++n) b[n] = *(const i32x4*)fB[n];
#pragma unroll
        for (int m = 0; m < 4; ++m)
#pragma unroll
            for (int n = 0; n < 4; ++n)
                acc[m][n] = __builtin_amdgcn_mfma_i32_16x16x64_i8(a[m], b[n], acc[m][n], 0, 0, 0);
        __syncthreads();
    }

    // epilogue: D lane mapping col = lane&15, row = (lane>>4)*4 + j  (verified m89/m101)
    const float ws = wscale_p[0];
#pragma unroll
    for (int m = 0; m < 4; ++m) {
        const int row0 = brow + wr * 64 + m * 16 + (lane >> 4) * 4;
#pragma unroll
        for (int n = 0; n < 4; ++n) {
            const int col = bcol + wc * 64 + n * 16 + r16;
            const float bv = bias[col];
#pragma unroll
            for (int j = 0; j < 4; ++j) {
                const int row = row0 + j;
                out[(size_t)row * OUT_F + col] =
                    (float)acc[m][n][j] * scales[row] * ws + bv;
            }
        }
    }
}

extern "C" void kernel_launch(void* const* d_in, const int* in_sizes, int n_in,
                              void* d_out, int out_size, void* d_ws, size_t ws_size,
                              hipStream_t stream) {
    const float* x       = (const float*)d_in[0];  // [4,2048,4096]
    const float* w_t     = (const float*)d_in[1];  // [4096,4096]
    const float* w_scale = (const float*)d_in[2];  // scalar
    const float* bias    = (const float*)d_in[3];  // [4096]
    float* out = (float*)d_out;

    // workspace layout: xq int8 [8192][4096] (32 MiB) | scales f32 [8192] (32 KiB)
    //                   | w8 int8 [4096][4096] (16 MiB)
    int8_t* xq     = (int8_t*)d_ws;
    float*  scales = (float*)((char*)d_ws + (size_t)T_ROWS * IN_F);
    int8_t* w8     = (int8_t*)((char*)d_ws + (size_t)T_ROWS * IN_F + T_ROWS * sizeof(float));

    quant_kernel<<<T_ROWS, 256, 0, stream>>>(x, xq, scales);
    wq_kernel<<<(OUT_F * IN_F) / (16 * 256), 256, 0, stream>>>(w_t, w8);

    dim3 grid(OUT_F / 128, T_ROWS / 128);
    gemm_kernel<<<grid, 256, 0, stream>>>(xq, w8, scales, bias, w_scale, out);
}

// Round 2
// 302.466 us; speedup vs baseline: 1.0771x; 1.0771x over previous
//
#include <hip/hip_runtime.h>
#include <stdint.h>

#define T_ROWS 8192
#define IN_F 4096
#define OUT_F 4096

using i32x4 = __attribute__((ext_vector_type(4))) int;

#define GLOBAL_AS __attribute__((address_space(1)))
#define LDS_AS __attribute__((address_space(3)))

static __device__ __forceinline__ void load_lds16(const void* g, void* l) {
    __builtin_amdgcn_global_load_lds((const GLOBAL_AS uint32_t*)g,
                                     (LDS_AS uint32_t*)l, 16, 0, 0);
}

// ---------------- Kernel 1: per-row absmax int8 quantization ----------------
__global__ __launch_bounds__(256) void quant_kernel(const float* __restrict__ x,
                                                    int8_t* __restrict__ xq,
                                                    float* __restrict__ scales) {
    const int row = blockIdx.x;
    const float* xr = x + (size_t)row * IN_F;
    const float4* xr4 = (const float4*)xr;

    float4 v[4];
    float amax = 0.0f;
#pragma unroll
    for (int i = 0; i < 4; ++i) {
        v[i] = xr4[threadIdx.x + 256 * i];
        amax = fmaxf(amax, fmaxf(fmaxf(fabsf(v[i].x), fabsf(v[i].y)),
                                 fmaxf(fabsf(v[i].z), fabsf(v[i].w))));
    }
#pragma unroll
    for (int off = 32; off; off >>= 1)
        amax = fmaxf(amax, __shfl_xor(amax, off, 64));
    __shared__ float smax[4];
    if ((threadIdx.x & 63) == 0) smax[threadIdx.x >> 6] = amax;
    __syncthreads();
    amax = fmaxf(fmaxf(smax[0], smax[1]), fmaxf(smax[2], smax[3]));

    const float act_scale = fmaxf(amax, 1e-10f) / 127.0f;
    if (threadIdx.x == 0) scales[row] = act_scale;

    int* xqr = (int*)(xq + (size_t)row * IN_F);
#pragma unroll
    for (int i = 0; i < 4; ++i) {
        int q0 = (int)fminf(fmaxf(rintf(v[i].x / act_scale), -127.0f), 127.0f);
        int q1 = (int)fminf(fmaxf(rintf(v[i].y / act_scale), -127.0f), 127.0f);
        int q2 = (int)fminf(fmaxf(rintf(v[i].z / act_scale), -127.0f), 127.0f);
        int q3 = (int)fminf(fmaxf(rintf(v[i].w / act_scale), -127.0f), 127.0f);
        int packed = (q0 & 0xff) | ((q1 & 0xff) << 8) | ((q2 & 0xff) << 16) | (q3 << 24);
        xqr[threadIdx.x + 256 * i] = packed;
    }
}

// ---------------- Kernel 2: ternary f32 weights -> int8 ----------------
__global__ __launch_bounds__(256) void wq_kernel(const float* __restrict__ w,
                                                 int8_t* __restrict__ w8) {
    const float4* w4 = (const float4*)w;
    int* o4 = (int*)w8;
    size_t base = (size_t)blockIdx.x * 1024 + threadIdx.x;
#pragma unroll
    for (int i = 0; i < 4; ++i) {
        size_t idx = base + 256 * i;
        float4 v = w4[idx];
        int q0 = (int)v.x, q1 = (int)v.y, q2 = (int)v.z, q3 = (int)v.w;
        o4[idx] = (q0 & 0xff) | ((q1 & 0xff) << 8) | ((q2 & 0xff) << 16) | (q3 << 24);
    }
}

// ---------------- Kernel 3: 256x256 8-phase int8 MFMA GEMM ----------------
// C[t][o] = sum_k xq[t][k] * w8[o][k]   (NT: both row-major, K contiguous)
// 512 threads = 8 waves (2M x 4N). Per-wave output 128x64, interleaved:
//   rows = m*32 + wr*16 (m=0..7), cols = n*64 + wc*16 (n=0..3).
// LDS per buffer per matrix: [8 chunks][256 rows][16B] = 32 KB; x2 buf x2 mat = 128 KB.
// Chunk-major layout is bank-conflict-free for the i8 fragment ds_read_b128
// (measured 0 conflicts in round 0) and linear per wave for global_load_lds.
// Schedule (iter t computes K-tiles 2t from buf0, 2t+1 from buf1):
//   p1:(b0,mh0,nh0)+stage b1.A1(K2t+1)   p2:(b0,mh0,nh1)+stage b1.B1(K2t+1)
//   p3:(b0,mh1,nh0)+stage b0.A0(K2t+2)   p4:(b0,mh1,nh1)+stage b0.B0(K2t+2) vmcnt(4)
//   p5:(b1,mh0,nh0)+stage b0.A1(K2t+2)   p6:(b1,mh0,nh1)+stage b0.B1(K2t+2)
//   p7:(b1,mh1,nh0)+stage b1.A0(K2t+3)   p8:(b1,mh1,nh1)+stage b1.B0(K2t+3) vmcnt(4)
// Each half-tile's last reader is >=1 phase before its restage (WAR safe via the
// trailing barrier), and vmcnt(4)+barrier at p4/p8 guarantees the next buffer's
// 4 half-tiles (oldest 8 of 12 outstanding loads) have landed.
__global__ __launch_bounds__(512, 2) void gemm_kernel(const int8_t* __restrict__ xq,
                                                      const int8_t* __restrict__ w8,
                                                      const float* __restrict__ scales,
                                                      const float* __restrict__ bias,
                                                      const float* __restrict__ wscale_p,
                                                      float* __restrict__ out) {
    __shared__ __align__(16) int8_t As[2 * 8 * 256 * 16];  // 64 KiB
    __shared__ __align__(16) int8_t Bs[2 * 8 * 256 * 16];  // 64 KiB

    const int tid = threadIdx.x;
    const int lane = tid & 63;
    const int w = tid >> 6;     // wave 0..7
    const int wr = w >> 2;      // 0..1
    const int wc = w & 3;       // 0..3
    const int l16 = lane & 15;
    const int lq = lane >> 4;   // 0..3

    // XCD-aware swizzle: nwg=512 (divisible by 8), contiguous chunk of 64 per XCD.
    int bid = blockIdx.x;
    bid = (bid & 7) * 64 + (bid >> 3);
    const int brow = (bid >> 4) * 256;  // 32 row tiles
    const int bcol = (bid & 15) * 256;  // 16 col tiles

    // staging source (per-lane): row = tilebase + h*128 + j*64 + lane; kbytes = kt*128 + w*16
    const int8_t* srcA = xq + (size_t)(brow + lane) * IN_F + w * 16;
    const int8_t* srcB = w8 + (size_t)(bcol + lane) * IN_F + w * 16;

    // fragment bases: A row = m*32 + wr*16 + l16, chunk = ks*4 + lq
    const int8_t* fA = As + (lq * 256 + wr * 16 + l16) * 16;
    const int8_t* fB = Bs + (lq * 256 + wc * 16 + l16) * 16;

#define STAGE(LDSA, SRC, BUF, H, KT) do {                                          \
    load_lds16((SRC) + (size_t)((H) * 128 + 0) * IN_F + (KT) * 128,                \
               (void*)((LDSA) + ((((BUF) * 8 + w) * 256 + (H) * 128 + 0) * 16)));  \
    load_lds16((SRC) + (size_t)((H) * 128 + 64) * IN_F + (KT) * 128,               \
               (void*)((LDSA) + ((((BUF) * 8 + w) * 256 + (H) * 128 + 64) * 16))); \
} while (0)

#define PHASE(BUF, MH, NH, STAGE_STMT, VM_STMT) do {                               \
    i32x4 a[4][2], b[2][2];                                                        \
    _Pragma("unroll") for (int m = 0; m < 4; ++m) {                                \
        a[m][0] = *(const i32x4*)(fA + (BUF) * 32768 + ((MH) * 4 + m) * 512);      \
        a[m][1] = *(const i32x4*)(fA + (BUF) * 32768 + 16384 + ((MH) * 4 + m) * 512); \
    }                                                                              \
    _Pragma("unroll") for (int n = 0; n < 2; ++n) {                                \
        b[n][0] = *(const i32x4*)(fB + (BUF) * 32768 + ((NH) * 2 + n) * 1024);     \
        b[n][1] = *(const i32x4*)(fB + (BUF) * 32768 + 16384 + ((NH) * 2 + n) * 1024); \
    }                                                                              \
    STAGE_STMT;                                                                    \
    __builtin_amdgcn_s_barrier();                                                  \
    asm volatile("s_waitcnt lgkmcnt(0)" ::: "memory");                             \
    __builtin_amdgcn_s_setprio(1);                                                 \
    _Pragma("unroll") for (int m = 0; m < 4; ++m)                                  \
    _Pragma("unroll") for (int n = 0; n < 2; ++n) {                                \
        acc[(MH) * 4 + m][(NH) * 2 + n] = __builtin_amdgcn_mfma_i32_16x16x64_i8(   \
            a[m][0], b[n][0], acc[(MH) * 4 + m][(NH) * 2 + n], 0, 0, 0);           \
        acc[(MH) * 4 + m][(NH) * 2 + n] = __builtin_amdgcn_mfma_i32_16x16x64_i8(   \
            a[m][1], b[n][1], acc[(MH) * 4 + m][(NH) * 2 + n], 0, 0, 0);           \
    }                                                                              \
    __builtin_amdgcn_s_setprio(0);                                                 \
    VM_STMT;                                                                       \
    __builtin_amdgcn_s_barrier();                                                  \
} while (0)

    i32x4 acc[8][4] = {};

    // Prologue: K-tile 0 -> buf0 (all 4 halves), K-tile 1 -> buf1 (A0, B0)
    STAGE(As, srcA, 0, 0, 0);
    STAGE(Bs, srcB, 0, 0, 0);
    STAGE(As, srcA, 0, 1, 0);
    STAGE(Bs, srcB, 0, 1, 0);
    STAGE(As, srcA, 1, 0, 1);
    STAGE(Bs, srcB, 1, 0, 1);
    asm volatile("s_waitcnt vmcnt(4)" ::: "memory");  // buf0's 8 loads done
    __builtin_amdgcn_s_barrier();

    for (int t = 0; t < 16; ++t) {
        const int k1 = 2 * t + 1;
        const int k2 = (2 * t + 2) & 31;  // wrap on last iter: harmless dead stages
        const int k3 = (2 * t + 3) & 31;
        PHASE(0, 0, 0, STAGE(As, srcA, 1, 1, k1), );
        PHASE(0, 0, 1, STAGE(Bs, srcB, 1, 1, k1), );
        PHASE(0, 1, 0, STAGE(As, srcA, 0, 0, k2), );
        PHASE(0, 1, 1, STAGE(Bs, srcB, 0, 0, k2),
              asm volatile("s_waitcnt vmcnt(4)" ::: "memory"));
        PHASE(1, 0, 0, STAGE(As, srcA, 0, 1, k2), );
        PHASE(1, 0, 1, STAGE(Bs, srcB, 0, 1, k2), );
        PHASE(1, 1, 0, STAGE(As, srcA, 1, 0, k3), );
        PHASE(1, 1, 1, STAGE(Bs, srcB, 1, 0, k3),
              asm volatile("s_waitcnt vmcnt(4)" ::: "memory"));
    }

    // Epilogue: D mapping col = lane&15, row = lq*4 + j within each 16x16 frag.
    const float ws = wscale_p[0];
#pragma unroll
    for (int m = 0; m < 8; ++m) {
        const int row0 = brow + m * 32 + wr * 16 + lq * 4;
#pragma unroll
        for (int j = 0; j < 4; ++j) {
            const int row = row0 + j;
            const float sc = scales[row] * ws;
#pragma unroll
            for (int n = 0; n < 4; ++n) {
                const int col = bcol + n * 64 + wc * 16 + l16;
                out[(size_t)row * OUT_F + col] = (float)acc[m][n][j] * sc + bias[col];
            }
        }
    }
#undef STAGE
#undef PHASE
}

extern "C" void kernel_launch(void* const* d_in, const int* in_sizes, int n_in,
                              void* d_out, int out_size, void* d_ws, size_t ws_size,
                              hipStream_t stream) {
    const float* x       = (const float*)d_in[0];
    const float* w_t     = (const float*)d_in[1];
    const float* w_scale = (const float*)d_in[2];
    const float* bias    = (const float*)d_in[3];
    float* out = (float*)d_out;

    int8_t* xq     = (int8_t*)d_ws;
    float*  scales = (float*)((char*)d_ws + (size_t)T_ROWS * IN_F);
    int8_t* w8     = (int8_t*)((char*)d_ws + (size_t)T_ROWS * IN_F + T_ROWS * sizeof(float));

    quant_kernel<<<T_ROWS, 256, 0, stream>>>(x, xq, scales);
    wq_kernel<<<(OUT_F * IN_F) / (16 * 256), 256, 0, stream>>>(w_t, w8);

    gemm_kernel<<<(T_ROWS / 256) * (OUT_F / 256), 512, 0, stream>>>(
        xq, w8, scales, bias, w_scale, out);
}

// Round 3
// 281.026 us; speedup vs baseline: 1.1592x; 1.0763x over previous
//
#include <hip/hip_runtime.h>
#include <stdint.h>

#define T_ROWS 8192
#define IN_F 4096
#define OUT_F 4096

using i32x4 = __attribute__((ext_vector_type(4))) int;

#define GLOBAL_AS __attribute__((address_space(1)))
#define LDS_AS __attribute__((address_space(3)))

static __device__ __forceinline__ void load_lds16(const void* g, void* l) {
    __builtin_amdgcn_global_load_lds((const GLOBAL_AS uint32_t*)g,
                                     (LDS_AS uint32_t*)l, 16, 0, 0);
}

// ---------------- Kernel 1: per-row absmax int8 quantization ----------------
__global__ __launch_bounds__(256) void quant_kernel(const float* __restrict__ x,
                                                    int8_t* __restrict__ xq,
                                                    float* __restrict__ scales) {
    const int row = blockIdx.x;
    const float* xr = x + (size_t)row * IN_F;
    const float4* xr4 = (const float4*)xr;

    float4 v[4];
    float amax = 0.0f;
#pragma unroll
    for (int i = 0; i < 4; ++i) {
        v[i] = xr4[threadIdx.x + 256 * i];
        amax = fmaxf(amax, fmaxf(fmaxf(fabsf(v[i].x), fabsf(v[i].y)),
                                 fmaxf(fabsf(v[i].z), fabsf(v[i].w))));
    }
#pragma unroll
    for (int off = 32; off; off >>= 1)
        amax = fmaxf(amax, __shfl_xor(amax, off, 64));
    __shared__ float smax[4];
    if ((threadIdx.x & 63) == 0) smax[threadIdx.x >> 6] = amax;
    __syncthreads();
    amax = fmaxf(fmaxf(smax[0], smax[1]), fmaxf(smax[2], smax[3]));

    const float act_scale = fmaxf(amax, 1e-10f) / 127.0f;
    if (threadIdx.x == 0) scales[row] = act_scale;

    int* xqr = (int*)(xq + (size_t)row * IN_F);
#pragma unroll
    for (int i = 0; i < 4; ++i) {
        int q0 = (int)fminf(fmaxf(rintf(v[i].x / act_scale), -127.0f), 127.0f);
        int q1 = (int)fminf(fmaxf(rintf(v[i].y / act_scale), -127.0f), 127.0f);
        int q2 = (int)fminf(fmaxf(rintf(v[i].z / act_scale), -127.0f), 127.0f);
        int q3 = (int)fminf(fmaxf(rintf(v[i].w / act_scale), -127.0f), 127.0f);
        int packed = (q0 & 0xff) | ((q1 & 0xff) << 8) | ((q2 & 0xff) << 16) | (q3 << 24);
        xqr[threadIdx.x + 256 * i] = packed;
    }
}

// ---------------- Kernel 2: ternary f32 weights -> int8 ----------------
__global__ __launch_bounds__(256) void wq_kernel(const float* __restrict__ w,
                                                 int8_t* __restrict__ w8) {
    const float4* w4 = (const float4*)w;
    int* o4 = (int*)w8;
    size_t base = (size_t)blockIdx.x * 1024 + threadIdx.x;
#pragma unroll
    for (int i = 0; i < 4; ++i) {
        size_t idx = base + 256 * i;
        float4 v = w4[idx];
        int q0 = (int)v.x, q1 = (int)v.y, q2 = (int)v.z, q3 = (int)v.w;
        o4[idx] = (q0 & 0xff) | ((q1 & 0xff) << 8) | ((q2 & 0xff) << 16) | (q3 << 24);
    }
}

// ---------------- Kernel 3: 256x256 8-phase int8 MFMA GEMM ----------------
// C[t][o] = sum_k xq[t][k] * w8[o][k]   (NT: both row-major, K contiguous)
// 512 threads = 8 waves (2M x 4N). Per-wave output 128x64 interleaved:
//   rows = m*32 + wr*16 (m=0..7), cols = n*64 + wc*16 (n=0..3).
// LDS: [buf 2][chunk 8][row 256][16B] per matrix = 64 KiB each, 128 KiB total.
// Snake quadrant order per buffer: (0,0)->(0,1)->(1,1)->(1,0) with
// register-persistent fragments: ra (A, 8 regs) re-read on MH change only;
// rb0/rb1 (B, 4 regs each) read once per buffer. Reads/phase: 12,4,8,0.
// Stage slots (one 16KB half-tile per phase), WAR-safe vs last reader:
//   p1: b1.A1(k_cur+1)  p2: b0.A0(k+2)  p3: b0.B0(k+2)  p4: b0.B1(k+2) vmcnt(6)
//   p5: b0.A1(k+2)      p6: b1.A0(k+3)  p7: b1.B0(k+3)  p8: b1.B1(k+3) vmcnt(6)
// vmcnt(6) at p4/p8 retires exactly the 4 half-tiles (8 loads) of the buffer
// about to be read, leaving the 3 newest stages (6 loads) in flight.
__global__ __launch_bounds__(512, 2) void gemm_kernel(const int8_t* __restrict__ xq,
                                                      const int8_t* __restrict__ w8,
                                                      const float* __restrict__ scales,
                                                      const float* __restrict__ bias,
                                                      const float* __restrict__ wscale_p,
                                                      float* __restrict__ out) {
    __shared__ __align__(16) int8_t As[2 * 8 * 256 * 16];  // 64 KiB
    __shared__ __align__(16) int8_t Bs[2 * 8 * 256 * 16];  // 64 KiB

    const int tid = threadIdx.x;
    const int lane = tid & 63;
    const int w = tid >> 6;     // wave 0..7
    const int wr = w >> 2;      // 0..1
    const int wc = w & 3;       // 0..3
    const int l16 = lane & 15;
    const int lq = lane >> 4;   // 0..3

    // XCD-aware swizzle: nwg=512 (divisible by 8), contiguous chunk of 64 per XCD.
    int bid = blockIdx.x;
    bid = (bid & 7) * 64 + (bid >> 3);
    const int brow = (bid >> 4) * 256;
    const int bcol = (bid & 15) * 256;

    const int8_t* srcA = xq + (size_t)(brow + lane) * IN_F + w * 16;
    const int8_t* srcB = w8 + (size_t)(bcol + lane) * IN_F + w * 16;

    const int8_t* fA = As + (lq * 256 + wr * 16 + l16) * 16;
    const int8_t* fB = Bs + (lq * 256 + wc * 16 + l16) * 16;

#define STAGE(LDSA, SRC, BUF, H, KT) do {                                          \
    load_lds16((SRC) + (size_t)((H) * 128 + 0) * IN_F + (KT) * 128,                \
               (void*)((LDSA) + ((((BUF) * 8 + w) * 256 + (H) * 128 + 0) * 16)));  \
    load_lds16((SRC) + (size_t)((H) * 128 + 64) * IN_F + (KT) * 128,               \
               (void*)((LDSA) + ((((BUF) * 8 + w) * 256 + (H) * 128 + 64) * 16))); \
} while (0)

#define READ_A(BUF, MH)                                                            \
    _Pragma("unroll") for (int m = 0; m < 4; ++m) {                                \
        ra[m][0] = *(const i32x4*)(fA + (BUF) * 32768 + ((MH) * 4 + m) * 512);     \
        ra[m][1] = *(const i32x4*)(fA + (BUF) * 32768 + 16384 + ((MH) * 4 + m) * 512); \
    }

#define READ_B(BUF, NH, RB)                                                        \
    _Pragma("unroll") for (int n = 0; n < 2; ++n) {                                \
        RB[n][0] = *(const i32x4*)(fB + (BUF) * 32768 + ((NH) * 2 + n) * 1024);    \
        RB[n][1] = *(const i32x4*)(fB + (BUF) * 32768 + 16384 + ((NH) * 2 + n) * 1024); \
    }

#define PHASE(READS, STAGE_STMT, MH, NH, RB, VM_STMT) do {                         \
    READS;                                                                         \
    STAGE_STMT;                                                                    \
    __builtin_amdgcn_s_barrier();                                                  \
    asm volatile("s_waitcnt lgkmcnt(0)" ::: "memory");                             \
    __builtin_amdgcn_s_setprio(1);                                                 \
    _Pragma("unroll") for (int m = 0; m < 4; ++m)                                  \
    _Pragma("unroll") for (int n = 0; n < 2; ++n) {                                \
        acc[(MH) * 4 + m][(NH) * 2 + n] = __builtin_amdgcn_mfma_i32_16x16x64_i8(   \
            ra[m][0], RB[n][0], acc[(MH) * 4 + m][(NH) * 2 + n], 0, 0, 0);         \
        acc[(MH) * 4 + m][(NH) * 2 + n] = __builtin_amdgcn_mfma_i32_16x16x64_i8(   \
            ra[m][1], RB[n][1], acc[(MH) * 4 + m][(NH) * 2 + n], 0, 0, 0);         \
    }                                                                              \
    __builtin_amdgcn_s_setprio(0);                                                 \
    VM_STMT;                                                                       \
    __builtin_amdgcn_s_barrier();                                                  \
} while (0)

    i32x4 acc[8][4] = {};
    i32x4 ra[4][2], rb0[2][2], rb1[2][2];

    // Prologue: buf0 <- K-tile 0 (4 halves), buf1 <- K-tile 1 (A0, B0, B1).
    STAGE(As, srcA, 0, 0, 0);
    STAGE(Bs, srcB, 0, 0, 0);
    STAGE(Bs, srcB, 0, 1, 0);
    STAGE(As, srcA, 0, 1, 0);
    STAGE(As, srcA, 1, 0, 1);
    STAGE(Bs, srcB, 1, 0, 1);
    STAGE(Bs, srcB, 1, 1, 1);
    asm volatile("s_waitcnt vmcnt(6)" ::: "memory");  // buf0's 8 loads done
    __builtin_amdgcn_s_barrier();

    for (int t = 0; t < 16; ++t) {
        const int k1 = 2 * t + 1;
        const int k2 = (2 * t + 2) & 31;  // wrap on last iter: dead-but-safe stages
        const int k3 = (2 * t + 3) & 31;
        PHASE(READ_A(0, 0); READ_B(0, 0, rb0), STAGE(As, srcA, 1, 1, k1), 0, 0, rb0, );
        PHASE(READ_B(0, 1, rb1),               STAGE(As, srcA, 0, 0, k2), 0, 1, rb1, );
        PHASE(READ_A(0, 1),                    STAGE(Bs, srcB, 0, 0, k2), 1, 1, rb1, );
        PHASE(,                                STAGE(Bs, srcB, 0, 1, k2), 1, 0, rb0,
              asm volatile("s_waitcnt vmcnt(6)" ::: "memory"));
        PHASE(READ_A(1, 0); READ_B(1, 0, rb0), STAGE(As, srcA, 0, 1, k2), 0, 0, rb0, );
        PHASE(READ_B(1, 1, rb1),               STAGE(As, srcA, 1, 0, k3), 0, 1, rb1, );
        PHASE(READ_A(1, 1),                    STAGE(Bs, srcB, 1, 0, k3), 1, 1, rb1, );
        PHASE(,                                STAGE(Bs, srcB, 1, 1, k3), 1, 0, rb0,
              asm volatile("s_waitcnt vmcnt(6)" ::: "memory"));
    }

    // Epilogue: D mapping col = lane&15, row = lq*4 + j within each 16x16 frag.
    const float ws = wscale_p[0];
#pragma unroll
    for (int m = 0; m < 8; ++m) {
        const int row0 = brow + m * 32 + wr * 16 + lq * 4;
#pragma unroll
        for (int j = 0; j < 4; ++j) {
            const int row = row0 + j;
            const float sc = scales[row] * ws;
#pragma unroll
            for (int n = 0; n < 4; ++n) {
                const int col = bcol + n * 64 + wc * 16 + l16;
                out[(size_t)row * OUT_F + col] = (float)acc[m][n][j] * sc + bias[col];
            }
        }
    }
#undef STAGE
#undef READ_A
#undef READ_B
#undef PHASE
}

extern "C" void kernel_launch(void* const* d_in, const int* in_sizes, int n_in,
                              void* d_out, int out_size, void* d_ws, size_t ws_size,
                              hipStream_t stream) {
    const float* x       = (const float*)d_in[0];
    const float* w_t     = (const float*)d_in[1];
    const float* w_scale = (const float*)d_in[2];
    const float* bias    = (const float*)d_in[3];
    float* out = (float*)d_out;

    int8_t* xq     = (int8_t*)d_ws;
    float*  scales = (float*)((char*)d_ws + (size_t)T_ROWS * IN_F);
    int8_t* w8     = (int8_t*)((char*)d_ws + (size_t)T_ROWS * IN_F + T_ROWS * sizeof(float));

    quant_kernel<<<T_ROWS, 256, 0, stream>>>(x, xq, scales);
    wq_kernel<<<(OUT_F * IN_F) / (16 * 256), 256, 0, stream>>>(w_t, w8);

    gemm_kernel<<<(T_ROWS / 256) * (OUT_F / 256), 512, 0, stream>>>(
        xq, w8, scales, bias, w_scale, out);
}

// Round 4
// 187.925 us; speedup vs baseline: 1.7335x; 1.4954x over previous
//
#include <hip/hip_runtime.h>
#include <stdint.h>

#define T_ROWS 8192
#define IN_F 4096
#define OUT_F 4096

using i32x4 = __attribute__((ext_vector_type(4))) int;

#define GLOBAL_AS __attribute__((address_space(1)))
#define LDS_AS __attribute__((address_space(3)))

static __device__ __forceinline__ void load_lds16(const void* g, void* l) {
    __builtin_amdgcn_global_load_lds((const GLOBAL_AS uint32_t*)g,
                                     (LDS_AS uint32_t*)l, 16, 0, 0);
}

// ---------------- Kernel 1: per-row absmax int8 quantization ----------------
__global__ __launch_bounds__(256) void quant_kernel(const float* __restrict__ x,
                                                    int8_t* __restrict__ xq,
                                                    float* __restrict__ scales) {
    const int row = blockIdx.x;
    const float* xr = x + (size_t)row * IN_F;
    const float4* xr4 = (const float4*)xr;

    float4 v[4];
    float amax = 0.0f;
#pragma unroll
    for (int i = 0; i < 4; ++i) {
        v[i] = xr4[threadIdx.x + 256 * i];
        amax = fmaxf(amax, fmaxf(fmaxf(fabsf(v[i].x), fabsf(v[i].y)),
                                 fmaxf(fabsf(v[i].z), fabsf(v[i].w))));
    }
#pragma unroll
    for (int off = 32; off; off >>= 1)
        amax = fmaxf(amax, __shfl_xor(amax, off, 64));
    __shared__ float smax[4];
    if ((threadIdx.x & 63) == 0) smax[threadIdx.x >> 6] = amax;
    __syncthreads();
    amax = fmaxf(fmaxf(smax[0], smax[1]), fmaxf(smax[2], smax[3]));

    const float act_scale = fmaxf(amax, 1e-10f) / 127.0f;
    if (threadIdx.x == 0) scales[row] = act_scale;

    int* xqr = (int*)(xq + (size_t)row * IN_F);
#pragma unroll
    for (int i = 0; i < 4; ++i) {
        int q0 = (int)fminf(fmaxf(rintf(v[i].x / act_scale), -127.0f), 127.0f);
        int q1 = (int)fminf(fmaxf(rintf(v[i].y / act_scale), -127.0f), 127.0f);
        int q2 = (int)fminf(fmaxf(rintf(v[i].z / act_scale), -127.0f), 127.0f);
        int q3 = (int)fminf(fmaxf(rintf(v[i].w / act_scale), -127.0f), 127.0f);
        int packed = (q0 & 0xff) | ((q1 & 0xff) << 8) | ((q2 & 0xff) << 16) | (q3 << 24);
        xqr[threadIdx.x + 256 * i] = packed;
    }
}

// ---------------- Kernel 2: ternary f32 weights -> int8 ----------------
__global__ __launch_bounds__(256) void wq_kernel(const float* __restrict__ w,
                                                 int8_t* __restrict__ w8) {
    const float4* w4 = (const float4*)w;
    int* o4 = (int*)w8;
    size_t base = (size_t)blockIdx.x * 1024 + threadIdx.x;
#pragma unroll
    for (int i = 0; i < 4; ++i) {
        size_t idx = base + 256 * i;
        float4 v = w4[idx];
        int q0 = (int)v.x, q1 = (int)v.y, q2 = (int)v.z, q3 = (int)v.w;
        o4[idx] = (q0 & 0xff) | ((q1 & 0xff) << 8) | ((q2 & 0xff) << 16) | (q3 << 24);
    }
}

// ---------------- Kernel 3: 256x256 8-phase int8 MFMA GEMM ----------------
// C[t][o] = sum_k xq[t][k] * w8[o][k]   (NT: both row-major, K contiguous)
// 512 threads = 8 waves (2M x 4N). Per-wave output 128x64 interleaved:
//   rows = m*32 + wr*16 (m=0..7), cols = n*64 + wc*16 (n=0..3).
// LDS: row-major [buf 2][row 256][128B] per matrix (32 KB/buf), XOR-swizzled:
//   16B slot s of row r lives at slot s ^ (r&7). Total 128 KiB.
// Staging (rule #21 both-sides): linear LDS dest via global_load_lds
//   (wave region = 8 rows x 128B contiguous in global => ideal coalescing,
//    16 cache lines/instr vs 64 with the old chunk-major layout) with the
//   per-lane global source pre-swizzled: lane l -> row +(l>>3),
//   K-slot (l&7)^(l>>3). Fragment ds_read applies the same XOR; per
//   16-lane quarter-group each bank is hit exactly 2x (free, m136).
// Snake quadrant order per buffer with register-persistent fragments
// (reads/phase: 12,4,8,0); stage slots + vmcnt(6) schedule as round 3
// (WAR/RAW verified; barrier pair per phase orders restage vs last read).
__global__ __launch_bounds__(512, 2) void gemm_kernel(const int8_t* __restrict__ xq,
                                                      const int8_t* __restrict__ w8,
                                                      const float* __restrict__ scales,
                                                      const float* __restrict__ bias,
                                                      const float* __restrict__ wscale_p,
                                                      float* __restrict__ out) {
    __shared__ __align__(16) int8_t As[2 * 256 * 128];  // 64 KiB
    __shared__ __align__(16) int8_t Bs[2 * 256 * 128];  // 64 KiB

    const int tid = threadIdx.x;
    const int lane = tid & 63;
    const int w = tid >> 6;     // wave 0..7
    const int wr = w >> 2;      // 0..1
    const int wc = w & 3;       // 0..3
    const int l16 = lane & 15;
    const int lq = lane >> 4;   // 0..3

    // XCD-aware swizzle: nwg=512 (divisible by 8), contiguous chunk of 64 per XCD.
    int bid = blockIdx.x;
    bid = (bid & 7) * 64 + (bid >> 3);
    const int brow = (bid >> 4) * 256;
    const int bcol = (bid & 15) * 256;

    // per-lane staging source: row +(lane>>3), K-slot (lane&7)^(lane>>3)
    const int lrow = lane >> 3;
    const int lslot = (lane & 7) ^ lrow;
    const int8_t* srcA = xq + (size_t)(brow + lrow) * IN_F + lslot * 16;
    const int8_t* srcB = w8 + (size_t)(bcol + lrow) * IN_F + lslot * 16;

    // per-lane fragment read pointers (ks=0 / ks=1 slots differ by ^4)
    const int sA = l16 & 7;
    const int8_t* pA0 = As + (wr * 16 + l16) * 128 + ((lq ^ sA) << 4);
    const int8_t* pA1 = As + (wr * 16 + l16) * 128 + (((lq ^ sA) ^ 4) << 4);
    const int8_t* pB0 = Bs + (wc * 16 + l16) * 128 + ((lq ^ sA) << 4);
    const int8_t* pB1 = Bs + (wc * 16 + l16) * 128 + (((lq ^ sA) ^ 4) << 4);

// Stage one half-tile (128 rows x 128B) of matrix LDSA from SRC, K-tile KT,
// into buffer BUF. Wave w covers 8-row regions {w, w+8} of the half.
#define STAGE(LDSA, SRC, BUF, H, KT) do {                                          \
    load_lds16((SRC) + (size_t)((H) * 128 + w * 8) * IN_F + (KT) * 128,            \
               (void*)((LDSA) + (BUF) * 32768 + ((H) * 16 + w) * 1024));           \
    load_lds16((SRC) + (size_t)((H) * 128 + (w + 8) * 8) * IN_F + (KT) * 128,      \
               (void*)((LDSA) + (BUF) * 32768 + ((H) * 16 + w + 8) * 1024));       \
} while (0)

#define READ_A(BUF, MH)                                                            \
    _Pragma("unroll") for (int m = 0; m < 4; ++m) {                                \
        ra[m][0] = *(const i32x4*)(pA0 + (BUF) * 32768 + ((MH) * 4 + m) * 4096);   \
        ra[m][1] = *(const i32x4*)(pA1 + (BUF) * 32768 + ((MH) * 4 + m) * 4096);   \
    }

#define READ_B(BUF, NH, RB)                                                        \
    _Pragma("unroll") for (int n = 0; n < 2; ++n) {                                \
        RB[n][0] = *(const i32x4*)(pB0 + (BUF) * 32768 + ((NH) * 2 + n) * 8192);   \
        RB[n][1] = *(const i32x4*)(pB1 + (BUF) * 32768 + ((NH) * 2 + n) * 8192);   \
    }

#define PHASE(READS, STAGE_STMT, MH, NH, RB, VM_STMT) do {                         \
    READS;                                                                         \
    STAGE_STMT;                                                                    \
    __builtin_amdgcn_s_barrier();                                                  \
    asm volatile("s_waitcnt lgkmcnt(0)" ::: "memory");                             \
    __builtin_amdgcn_s_setprio(1);                                                 \
    _Pragma("unroll") for (int m = 0; m < 4; ++m)                                  \
    _Pragma("unroll") for (int n = 0; n < 2; ++n) {                                \
        acc[(MH) * 4 + m][(NH) * 2 + n] = __builtin_amdgcn_mfma_i32_16x16x64_i8(   \
            ra[m][0], RB[n][0], acc[(MH) * 4 + m][(NH) * 2 + n], 0, 0, 0);         \
        acc[(MH) * 4 + m][(NH) * 2 + n] = __builtin_amdgcn_mfma_i32_16x16x64_i8(   \
            ra[m][1], RB[n][1], acc[(MH) * 4 + m][(NH) * 2 + n], 0, 0, 0);         \
    }                                                                              \
    __builtin_amdgcn_s_setprio(0);                                                 \
    VM_STMT;                                                                       \
    __builtin_amdgcn_s_barrier();                                                  \
} while (0)

    i32x4 acc[8][4] = {};
    i32x4 ra[4][2], rb0[2][2], rb1[2][2];

    // Prologue: buf0 <- K-tile 0 (4 halves), buf1 <- K-tile 1 (A0, B0, B1).
    STAGE(As, srcA, 0, 0, 0);
    STAGE(Bs, srcB, 0, 0, 0);
    STAGE(Bs, srcB, 0, 1, 0);
    STAGE(As, srcA, 0, 1, 0);
    STAGE(As, srcA, 1, 0, 1);
    STAGE(Bs, srcB, 1, 0, 1);
    STAGE(Bs, srcB, 1, 1, 1);
    asm volatile("s_waitcnt vmcnt(6)" ::: "memory");  // buf0's 8 loads done
    __builtin_amdgcn_s_barrier();

    for (int t = 0; t < 16; ++t) {
        const int k1 = 2 * t + 1;
        const int k2 = (2 * t + 2) & 31;  // wrap on last iter: dead-but-safe stages
        const int k3 = (2 * t + 3) & 31;
        PHASE(READ_A(0, 0); READ_B(0, 0, rb0), STAGE(As, srcA, 1, 1, k1), 0, 0, rb0, );
        PHASE(READ_B(0, 1, rb1),               STAGE(As, srcA, 0, 0, k2), 0, 1, rb1, );
        PHASE(READ_A(0, 1),                    STAGE(Bs, srcB, 0, 0, k2), 1, 1, rb1, );
        PHASE(,                                STAGE(Bs, srcB, 0, 1, k2), 1, 0, rb0,
              asm volatile("s_waitcnt vmcnt(6)" ::: "memory"));
        PHASE(READ_A(1, 0); READ_B(1, 0, rb0), STAGE(As, srcA, 0, 1, k2), 0, 0, rb0, );
        PHASE(READ_B(1, 1, rb1),               STAGE(As, srcA, 1, 0, k3), 0, 1, rb1, );
        PHASE(READ_A(1, 1),                    STAGE(Bs, srcB, 1, 0, k3), 1, 1, rb1, );
        PHASE(,                                STAGE(Bs, srcB, 1, 1, k3), 1, 0, rb0,
              asm volatile("s_waitcnt vmcnt(6)" ::: "memory"));
    }

    // Epilogue: D mapping col = lane&15, row = lq*4 + j within each 16x16 frag.
    const float ws = wscale_p[0];
#pragma unroll
    for (int m = 0; m < 8; ++m) {
        const int row0 = brow + m * 32 + wr * 16 + lq * 4;
#pragma unroll
        for (int j = 0; j < 4; ++j) {
            const int row = row0 + j;
            const float sc = scales[row] * ws;
#pragma unroll
            for (int n = 0; n < 4; ++n) {
                const int col = bcol + n * 64 + wc * 16 + l16;
                out[(size_t)row * OUT_F + col] = (float)acc[m][n][j] * sc + bias[col];
            }
        }
    }
#undef STAGE
#undef READ_A
#undef READ_B
#undef PHASE
}

extern "C" void kernel_launch(void* const* d_in, const int* in_sizes, int n_in,
                              void* d_out, int out_size, void* d_ws, size_t ws_size,
                              hipStream_t stream) {
    const float* x       = (const float*)d_in[0];
    const float* w_t     = (const float*)d_in[1];
    const float* w_scale = (const float*)d_in[2];
    const float* bias    = (const float*)d_in[3];
    float* out = (float*)d_out;

    int8_t* xq     = (int8_t*)d_ws;
    float*  scales = (float*)((char*)d_ws + (size_t)T_ROWS * IN_F);
    int8_t* w8     = (int8_t*)((char*)d_ws + (size_t)T_ROWS * IN_F + T_ROWS * sizeof(float));

    quant_kernel<<<T_ROWS, 256, 0, stream>>>(x, xq, scales);
    wq_kernel<<<(OUT_F * IN_F) / (16 * 256), 256, 0, stream>>>(w_t, w8);

    gemm_kernel<<<(T_ROWS / 256) * (OUT_F / 256), 512, 0, stream>>>(
        xq, w8, scales, bias, w_scale, out);
}

// Round 5
// 184.609 us; speedup vs baseline: 1.7647x; 1.0180x over previous
//
#include <hip/hip_runtime.h>
#include <stdint.h>

#define T_ROWS 8192
#define IN_F 4096
#define OUT_F 4096

using i32x4 = __attribute__((ext_vector_type(4))) int;

#define GLOBAL_AS __attribute__((address_space(1)))
#define LDS_AS __attribute__((address_space(3)))

static __device__ __forceinline__ void load_lds16(const void* g, void* l) {
    __builtin_amdgcn_global_load_lds((const GLOBAL_AS uint32_t*)g,
                                     (LDS_AS uint32_t*)l, 16, 0, 0);
}

// -------- Kernel 1: fused prep: per-row int8 quant (blocks 0..8191) +
//                    ternary f32 -> int8 weight pack (blocks 8192..12287) --------
__global__ __launch_bounds__(256) void prep_kernel(const float* __restrict__ x,
                                                   int8_t* __restrict__ xq,
                                                   float* __restrict__ scales,
                                                   const float* __restrict__ w,
                                                   int8_t* __restrict__ w8) {
    if (blockIdx.x < T_ROWS) {
        const int row = blockIdx.x;
        const float* xr = x + (size_t)row * IN_F;
        const float4* xr4 = (const float4*)xr;

        float4 v[4];
        float amax = 0.0f;
#pragma unroll
        for (int i = 0; i < 4; ++i) {
            v[i] = xr4[threadIdx.x + 256 * i];
            amax = fmaxf(amax, fmaxf(fmaxf(fabsf(v[i].x), fabsf(v[i].y)),
                                     fmaxf(fabsf(v[i].z), fabsf(v[i].w))));
        }
#pragma unroll
        for (int off = 32; off; off >>= 1)
            amax = fmaxf(amax, __shfl_xor(amax, off, 64));
        __shared__ float smax[4];
        if ((threadIdx.x & 63) == 0) smax[threadIdx.x >> 6] = amax;
        __syncthreads();
        amax = fmaxf(fmaxf(smax[0], smax[1]), fmaxf(smax[2], smax[3]));

        const float act_scale = fmaxf(amax, 1e-10f) / 127.0f;
        if (threadIdx.x == 0) scales[row] = act_scale;

        int* xqr = (int*)(xq + (size_t)row * IN_F);
#pragma unroll
        for (int i = 0; i < 4; ++i) {
            int q0 = (int)fminf(fmaxf(rintf(v[i].x / act_scale), -127.0f), 127.0f);
            int q1 = (int)fminf(fmaxf(rintf(v[i].y / act_scale), -127.0f), 127.0f);
            int q2 = (int)fminf(fmaxf(rintf(v[i].z / act_scale), -127.0f), 127.0f);
            int q3 = (int)fminf(fmaxf(rintf(v[i].w / act_scale), -127.0f), 127.0f);
            int packed = (q0 & 0xff) | ((q1 & 0xff) << 8) | ((q2 & 0xff) << 16) | (q3 << 24);
            xqr[threadIdx.x + 256 * i] = packed;
        }
    } else {
        const float4* w4 = (const float4*)w;
        int* o4 = (int*)w8;
        size_t base = (size_t)(blockIdx.x - T_ROWS) * 1024 + threadIdx.x;
#pragma unroll
        for (int i = 0; i < 4; ++i) {
            size_t idx = base + 256 * i;
            float4 v = w4[idx];
            int q0 = (int)v.x, q1 = (int)v.y, q2 = (int)v.z, q3 = (int)v.w;
            o4[idx] = (q0 & 0xff) | ((q1 & 0xff) << 8) | ((q2 & 0xff) << 16) | (q3 << 24);
        }
    }
}

// ---------------- Kernel 2: 256x256 8-phase int8 MFMA GEMM ----------------
// C[t][o] = sum_k xq[t][k] * w8[o][k]   (NT: both row-major, K contiguous)
// 512 threads = 8 waves (2M x 4N). Per-wave output 128x64 interleaved:
//   rows = m*32 + wr*16 (m=0..7), cols = n*64 + wc*16 (n=0..3).
// LDS: row-major [buf 2][row 256][128B] per matrix (32 KB/buf), XOR-swizzled:
//   16B slot s of row r lives at slot s ^ (r&7). Total 128 KiB.
// Staging: linear LDS dest via global_load_lds (8 rows x 128B contiguous per
// instr) with per-lane pre-swizzled global source (rule #21 both-sides).
// Snake quadrant order per buffer with register-persistent fragments
// (reads/phase 12/4/8/0); stage slots + vmcnt(6) as rounds 3-4.
// NO manual lgkmcnt(0): the compiler inserts fine-grained staggered lgkmcnt
// before each fragment's first MFMA use, so later reads land under earlier
// MFMAs. Cross-phase ordering: every read is consumed (hw-waited) before its
// phase's trailing barrier; a zero-cost compiler fence after that barrier
// prevents hoisting the next phase's reads above it. vmcnt asms keep their
// "memory" clobber, blocking hoists above the staging guarantees.
__global__ __launch_bounds__(512, 2) void gemm_kernel(const int8_t* __restrict__ xq,
                                                      const int8_t* __restrict__ w8,
                                                      const float* __restrict__ scales,
                                                      const float* __restrict__ bias,
                                                      const float* __restrict__ wscale_p,
                                                      float* __restrict__ out) {
    __shared__ __align__(16) int8_t As[2 * 256 * 128];  // 64 KiB
    __shared__ __align__(16) int8_t Bs[2 * 256 * 128];  // 64 KiB

    const int tid = threadIdx.x;
    const int lane = tid & 63;
    const int w = tid >> 6;     // wave 0..7
    const int wr = w >> 2;      // 0..1
    const int wc = w & 3;       // 0..3
    const int l16 = lane & 15;
    const int lq = lane >> 4;   // 0..3

    // XCD-aware swizzle: nwg=512 (divisible by 8), contiguous chunk of 64 per XCD.
    int bid = blockIdx.x;
    bid = (bid & 7) * 64 + (bid >> 3);
    const int brow = (bid >> 4) * 256;
    const int bcol = (bid & 15) * 256;

    // per-lane staging source: row +(lane>>3), K-slot (lane&7)^(lane>>3)
    const int lrow = lane >> 3;
    const int lslot = (lane & 7) ^ lrow;
    const int8_t* srcA = xq + (size_t)(brow + lrow) * IN_F + lslot * 16;
    const int8_t* srcB = w8 + (size_t)(bcol + lrow) * IN_F + lslot * 16;

    // per-lane fragment read pointers (ks=0 / ks=1 slots differ by ^4)
    const int sA = l16 & 7;
    const int8_t* pA0 = As + (wr * 16 + l16) * 128 + ((lq ^ sA) << 4);
    const int8_t* pA1 = As + (wr * 16 + l16) * 128 + (((lq ^ sA) ^ 4) << 4);
    const int8_t* pB0 = Bs + (wc * 16 + l16) * 128 + ((lq ^ sA) << 4);
    const int8_t* pB1 = Bs + (wc * 16 + l16) * 128 + (((lq ^ sA) ^ 4) << 4);

// Stage one half-tile (128 rows x 128B) of matrix LDSA from SRC, K-tile KT,
// into buffer BUF. Wave w covers 8-row regions {w, w+8} of the half.
#define STAGE(LDSA, SRC, BUF, H, KT) do {                                          \
    load_lds16((SRC) + (size_t)((H) * 128 + w * 8) * IN_F + (KT) * 128,            \
               (void*)((LDSA) + (BUF) * 32768 + ((H) * 16 + w) * 1024));           \
    load_lds16((SRC) + (size_t)((H) * 128 + (w + 8) * 8) * IN_F + (KT) * 128,      \
               (void*)((LDSA) + (BUF) * 32768 + ((H) * 16 + w + 8) * 1024));       \
} while (0)

#define READ_A(BUF, MH)                                                            \
    _Pragma("unroll") for (int m = 0; m < 4; ++m) {                                \
        ra[m][0] = *(const i32x4*)(pA0 + (BUF) * 32768 + ((MH) * 4 + m) * 4096);   \
        ra[m][1] = *(const i32x4*)(pA1 + (BUF) * 32768 + ((MH) * 4 + m) * 4096);   \
    }

#define READ_B(BUF, NH, RB)                                                        \
    _Pragma("unroll") for (int n = 0; n < 2; ++n) {                                \
        RB[n][0] = *(const i32x4*)(pB0 + (BUF) * 32768 + ((NH) * 2 + n) * 8192);   \
        RB[n][1] = *(const i32x4*)(pB1 + (BUF) * 32768 + ((NH) * 2 + n) * 8192);   \
    }

#define PHASE(READS, STAGE_STMT, MH, NH, RB, VM_STMT) do {                         \
    READS;                                                                         \
    STAGE_STMT;                                                                    \
    __builtin_amdgcn_s_barrier();                                                  \
    __builtin_amdgcn_s_setprio(1);                                                 \
    _Pragma("unroll") for (int m = 0; m < 4; ++m)                                  \
    _Pragma("unroll") for (int n = 0; n < 2; ++n) {                                \
        acc[(MH) * 4 + m][(NH) * 2 + n] = __builtin_amdgcn_mfma_i32_16x16x64_i8(   \
            ra[m][0], RB[n][0], acc[(MH) * 4 + m][(NH) * 2 + n], 0, 0, 0);         \
        acc[(MH) * 4 + m][(NH) * 2 + n] = __builtin_amdgcn_mfma_i32_16x16x64_i8(   \
            ra[m][1], RB[n][1], acc[(MH) * 4 + m][(NH) * 2 + n], 0, 0, 0);         \
    }                                                                              \
    __builtin_amdgcn_s_setprio(0);                                                 \
    VM_STMT;                                                                       \
    __builtin_amdgcn_s_barrier();                                                  \
    asm volatile("" ::: "memory");                                                 \
} while (0)

    i32x4 acc[8][4] = {};
    i32x4 ra[4][2], rb0[2][2], rb1[2][2];

    // Prologue: buf0 <- K-tile 0 (4 halves), buf1 <- K-tile 1 (A0, B0, B1).
    STAGE(As, srcA, 0, 0, 0);
    STAGE(Bs, srcB, 0, 0, 0);
    STAGE(Bs, srcB, 0, 1, 0);
    STAGE(As, srcA, 0, 1, 0);
    STAGE(As, srcA, 1, 0, 1);
    STAGE(Bs, srcB, 1, 0, 1);
    STAGE(Bs, srcB, 1, 1, 1);
    asm volatile("s_waitcnt vmcnt(6)" ::: "memory");  // buf0's 8 loads done
    __builtin_amdgcn_s_barrier();
    asm volatile("" ::: "memory");

    for (int t = 0; t < 16; ++t) {
        const int k1 = 2 * t + 1;
        const int k2 = (2 * t + 2) & 31;  // wrap on last iter: dead-but-safe stages
        const int k3 = (2 * t + 3) & 31;
        PHASE(READ_A(0, 0); READ_B(0, 0, rb0), STAGE(As, srcA, 1, 1, k1), 0, 0, rb0, );
        PHASE(READ_B(0, 1, rb1),               STAGE(As, srcA, 0, 0, k2), 0, 1, rb1, );
        PHASE(READ_A(0, 1),                    STAGE(Bs, srcB, 0, 0, k2), 1, 1, rb1, );
        PHASE(,                                STAGE(Bs, srcB, 0, 1, k2), 1, 0, rb0,
              asm volatile("s_waitcnt vmcnt(6)" ::: "memory"));
        PHASE(READ_A(1, 0); READ_B(1, 0, rb0), STAGE(As, srcA, 0, 1, k2), 0, 0, rb0, );
        PHASE(READ_B(1, 1, rb1),               STAGE(As, srcA, 1, 0, k3), 0, 1, rb1, );
        PHASE(READ_A(1, 1),                    STAGE(Bs, srcB, 1, 0, k3), 1, 1, rb1, );
        PHASE(,                                STAGE(Bs, srcB, 1, 1, k3), 1, 0, rb0,
              asm volatile("s_waitcnt vmcnt(6)" ::: "memory"));
    }

    // Epilogue: D mapping col = lane&15, row = lq*4 + j within each 16x16 frag.
    const float ws = wscale_p[0];
#pragma unroll
    for (int m = 0; m < 8; ++m) {
        const int row0 = brow + m * 32 + wr * 16 + lq * 4;
#pragma unroll
        for (int j = 0; j < 4; ++j) {
            const int row = row0 + j;
            const float sc = scales[row] * ws;
#pragma unroll
            for (int n = 0; n < 4; ++n) {
                const int col = bcol + n * 64 + wc * 16 + l16;
                out[(size_t)row * OUT_F + col] = (float)acc[m][n][j] * sc + bias[col];
            }
        }
    }
#undef STAGE
#undef READ_A
#undef READ_B
#undef PHASE
}

extern "C" void kernel_launch(void* const* d_in, const int* in_sizes, int n_in,
                              void* d_out, int out_size, void* d_ws, size_t ws_size,
                              hipStream_t stream) {
    const float* x       = (const float*)d_in[0];
    const float* w_t     = (const float*)d_in[1];
    const float* w_scale = (const float*)d_in[2];
    const float* bias    = (const float*)d_in[3];
    float* out = (float*)d_out;

    int8_t* xq     = (int8_t*)d_ws;
    float*  scales = (float*)((char*)d_ws + (size_t)T_ROWS * IN_F);
    int8_t* w8     = (int8_t*)((char*)d_ws + (size_t)T_ROWS * IN_F + T_ROWS * sizeof(float));

    prep_kernel<<<T_ROWS + (OUT_F * IN_F) / (16 * 256), 256, 0, stream>>>(
        x, xq, scales, w_t, w8);

    gemm_kernel<<<(T_ROWS / 256) * (OUT_F / 256), 512, 0, stream>>>(
        xq, w8, scales, bias, w_scale, out);
}

// Round 6
// 178.914 us; speedup vs baseline: 1.8208x; 1.0318x over previous
//
#include <hip/hip_runtime.h>
#include <stdint.h>

#define T_ROWS 8192
#define IN_F 4096
#define OUT_F 4096

using i32x4 = __attribute__((ext_vector_type(4))) int;

#define GLOBAL_AS __attribute__((address_space(1)))
#define LDS_AS __attribute__((address_space(3)))

static __device__ __forceinline__ void load_lds16(const void* g, void* l) {
    __builtin_amdgcn_global_load_lds((const GLOBAL_AS uint32_t*)g,
                                     (LDS_AS uint32_t*)l, 16, 0, 0);
}

// -------- Kernel 1: fused prep: per-row int8 quant (blocks 0..8191) +
//                    ternary f32 -> int8 weight pack (blocks 8192..12287) --------
__global__ __launch_bounds__(256) void prep_kernel(const float* __restrict__ x,
                                                   int8_t* __restrict__ xq,
                                                   float* __restrict__ scales,
                                                   const float* __restrict__ w,
                                                   int8_t* __restrict__ w8) {
    if (blockIdx.x < T_ROWS) {
        const int row = blockIdx.x;
        const float* xr = x + (size_t)row * IN_F;
        const float4* xr4 = (const float4*)xr;

        float4 v[4];
        float amax = 0.0f;
#pragma unroll
        for (int i = 0; i < 4; ++i) {
            v[i] = xr4[threadIdx.x + 256 * i];
            amax = fmaxf(amax, fmaxf(fmaxf(fabsf(v[i].x), fabsf(v[i].y)),
                                     fmaxf(fabsf(v[i].z), fabsf(v[i].w))));
        }
#pragma unroll
        for (int off = 32; off; off >>= 1)
            amax = fmaxf(amax, __shfl_xor(amax, off, 64));
        __shared__ float smax[4];
        if ((threadIdx.x & 63) == 0) smax[threadIdx.x >> 6] = amax;
        __syncthreads();
        amax = fmaxf(fmaxf(smax[0], smax[1]), fmaxf(smax[2], smax[3]));

        const float act_scale = fmaxf(amax, 1e-10f) / 127.0f;
        if (threadIdx.x == 0) scales[row] = act_scale;

        int* xqr = (int*)(xq + (size_t)row * IN_F);
#pragma unroll
        for (int i = 0; i < 4; ++i) {
            int q0 = (int)fminf(fmaxf(rintf(v[i].x / act_scale), -127.0f), 127.0f);
            int q1 = (int)fminf(fmaxf(rintf(v[i].y / act_scale), -127.0f), 127.0f);
            int q2 = (int)fminf(fmaxf(rintf(v[i].z / act_scale), -127.0f), 127.0f);
            int q3 = (int)fminf(fmaxf(rintf(v[i].w / act_scale), -127.0f), 127.0f);
            int packed = (q0 & 0xff) | ((q1 & 0xff) << 8) | ((q2 & 0xff) << 16) | (q3 << 24);
            xqr[threadIdx.x + 256 * i] = packed;
        }
    } else {
        const float4* w4 = (const float4*)w;
        int* o4 = (int*)w8;
        size_t base = (size_t)(blockIdx.x - T_ROWS) * 1024 + threadIdx.x;
#pragma unroll
        for (int i = 0; i < 4; ++i) {
            size_t idx = base + 256 * i;
            float4 v = w4[idx];
            int q0 = (int)v.x, q1 = (int)v.y, q2 = (int)v.z, q3 = (int)v.w;
            o4[idx] = (q0 & 0xff) | ((q1 & 0xff) << 8) | ((q2 & 0xff) << 16) | (q3 << 24);
        }
    }
}

// ---------------- Kernel 2: 256x256 8-phase int8 MFMA GEMM ----------------
// C[t][o] = sum_k xq[t][k] * w8[o][k]   (NT: both row-major, K contiguous)
// 512 threads = 8 waves (2M x 4N). Per-wave output 128x64 interleaved:
//   rows = m*32 + wr*16 (m=0..7), cols = n*64 + wc*16 (n=0..3).
// LDS: row-major [buf 2][row 256][128B] per matrix (32 KB/buf), XOR-swizzled:
//   16B slot s of row r lives at slot s ^ (r&7). Total 128 KiB.
// Staging: linear LDS dest via global_load_lds (8 rows x 128B contiguous per
// instr) with per-lane pre-swizzled global source (rule #21 both-sides).
// Snake quadrant order per buffer with register-persistent fragments
// (reads/phase 12/4/8/0, B issued before A); stage slots + vmcnt(6) as r3-5.
// SINGLE (trailing) barrier per phase: reads/stage/MFMA of a phase share one
// region so the compiler staggers lgkm waits and waves slip -> LDS drain hides
// under MFMA (max not sum). Hazards all route through trailing barriers:
//   RAW stage->read: vmcnt(6) at p4/p8 + that phase's trailing barrier.
//   WAR read->restage: reads are hw-waited before their consuming MFMA, hence
//     before the phase's trailing barrier; the conflicting restage issues in a
//     later phase (verified per-phase, incl. p5-read(As buf1)/p6-stage(As buf1)).
// The compiler fence after each trailing barrier pins ops inside their phase
// (keeps the vmcnt-counting proof exact; blocks read-hoist between vmcnt and
// barrier per rule #18).
__global__ __launch_bounds__(512, 2) void gemm_kernel(const int8_t* __restrict__ xq,
                                                      const int8_t* __restrict__ w8,
                                                      const float* __restrict__ scales,
                                                      const float* __restrict__ bias,
                                                      const float* __restrict__ wscale_p,
                                                      float* __restrict__ out) {
    __shared__ __align__(16) int8_t As[2 * 256 * 128];  // 64 KiB
    __shared__ __align__(16) int8_t Bs[2 * 256 * 128];  // 64 KiB

    const int tid = threadIdx.x;
    const int lane = tid & 63;
    const int w = tid >> 6;     // wave 0..7
    const int wr = w >> 2;      // 0..1
    const int wc = w & 3;       // 0..3
    const int l16 = lane & 15;
    const int lq = lane >> 4;   // 0..3

    // XCD-aware swizzle: nwg=512 (divisible by 8), contiguous chunk of 64 per XCD.
    int bid = blockIdx.x;
    bid = (bid & 7) * 64 + (bid >> 3);
    const int brow = (bid >> 4) * 256;
    const int bcol = (bid & 15) * 256;

    // per-lane staging source: row +(lane>>3), K-slot (lane&7)^(lane>>3)
    const int lrow = lane >> 3;
    const int lslot = (lane & 7) ^ lrow;
    const int8_t* srcA = xq + (size_t)(brow + lrow) * IN_F + lslot * 16;
    const int8_t* srcB = w8 + (size_t)(bcol + lrow) * IN_F + lslot * 16;

    // per-lane fragment read pointers (ks=0 / ks=1 slots differ by ^4)
    const int sA = l16 & 7;
    const int8_t* pA0 = As + (wr * 16 + l16) * 128 + ((lq ^ sA) << 4);
    const int8_t* pA1 = As + (wr * 16 + l16) * 128 + (((lq ^ sA) ^ 4) << 4);
    const int8_t* pB0 = Bs + (wc * 16 + l16) * 128 + ((lq ^ sA) << 4);
    const int8_t* pB1 = Bs + (wc * 16 + l16) * 128 + (((lq ^ sA) ^ 4) << 4);

// Stage one half-tile (128 rows x 128B) of matrix LDSA from SRC, K-tile KT,
// into buffer BUF. Wave w covers 8-row regions {w, w+8} of the half.
#define STAGE(LDSA, SRC, BUF, H, KT) do {                                          \
    load_lds16((SRC) + (size_t)((H) * 128 + w * 8) * IN_F + (KT) * 128,            \
               (void*)((LDSA) + (BUF) * 32768 + ((H) * 16 + w) * 1024));           \
    load_lds16((SRC) + (size_t)((H) * 128 + (w + 8) * 8) * IN_F + (KT) * 128,      \
               (void*)((LDSA) + (BUF) * 32768 + ((H) * 16 + w + 8) * 1024));       \
} while (0)

#define READ_A(BUF, MH)                                                            \
    _Pragma("unroll") for (int m = 0; m < 4; ++m) {                                \
        ra[m][0] = *(const i32x4*)(pA0 + (BUF) * 32768 + ((MH) * 4 + m) * 4096);   \
        ra[m][1] = *(const i32x4*)(pA1 + (BUF) * 32768 + ((MH) * 4 + m) * 4096);   \
    }

#define READ_B(BUF, NH, RB)                                                        \
    _Pragma("unroll") for (int n = 0; n < 2; ++n) {                                \
        RB[n][0] = *(const i32x4*)(pB0 + (BUF) * 32768 + ((NH) * 2 + n) * 8192);   \
        RB[n][1] = *(const i32x4*)(pB1 + (BUF) * 32768 + ((NH) * 2 + n) * 8192);   \
    }

#define PHASE(READS, STAGE_STMT, MH, NH, RB, VM_STMT) do {                         \
    READS;                                                                         \
    STAGE_STMT;                                                                    \
    __builtin_amdgcn_s_setprio(1);                                                 \
    _Pragma("unroll") for (int m = 0; m < 4; ++m)                                  \
    _Pragma("unroll") for (int n = 0; n < 2; ++n) {                                \
        acc[(MH) * 4 + m][(NH) * 2 + n] = __builtin_amdgcn_mfma_i32_16x16x64_i8(   \
            ra[m][0], RB[n][0], acc[(MH) * 4 + m][(NH) * 2 + n], 0, 0, 0);         \
        acc[(MH) * 4 + m][(NH) * 2 + n] = __builtin_amdgcn_mfma_i32_16x16x64_i8(   \
            ra[m][1], RB[n][1], acc[(MH) * 4 + m][(NH) * 2 + n], 0, 0, 0);         \
    }                                                                              \
    __builtin_amdgcn_s_setprio(0);                                                 \
    VM_STMT;                                                                       \
    __builtin_amdgcn_s_barrier();                                                  \
    asm volatile("" ::: "memory");                                                 \
} while (0)

    i32x4 acc[8][4] = {};
    i32x4 ra[4][2], rb0[2][2], rb1[2][2];

    // Prologue: buf0 <- K-tile 0 (4 halves), buf1 <- K-tile 1 (A0, B0, B1).
    STAGE(As, srcA, 0, 0, 0);
    STAGE(Bs, srcB, 0, 0, 0);
    STAGE(Bs, srcB, 0, 1, 0);
    STAGE(As, srcA, 0, 1, 0);
    STAGE(As, srcA, 1, 0, 1);
    STAGE(Bs, srcB, 1, 0, 1);
    STAGE(Bs, srcB, 1, 1, 1);
    asm volatile("s_waitcnt vmcnt(6)" ::: "memory");  // buf0's 8 loads done
    __builtin_amdgcn_s_barrier();
    asm volatile("" ::: "memory");

    for (int t = 0; t < 16; ++t) {
        const int k1 = 2 * t + 1;
        const int k2 = (2 * t + 2) & 31;  // wrap on last iter: dead-but-safe stages
        const int k3 = (2 * t + 3) & 31;
        PHASE(READ_B(0, 0, rb0); READ_A(0, 0), STAGE(As, srcA, 1, 1, k1), 0, 0, rb0, );
        PHASE(READ_B(0, 1, rb1),               STAGE(As, srcA, 0, 0, k2), 0, 1, rb1, );
        PHASE(READ_A(0, 1),                    STAGE(Bs, srcB, 0, 0, k2), 1, 1, rb1, );
        PHASE(,                                STAGE(Bs, srcB, 0, 1, k2), 1, 0, rb0,
              asm volatile("s_waitcnt vmcnt(6)" ::: "memory"));
        PHASE(READ_B(1, 0, rb0); READ_A(1, 0), STAGE(As, srcA, 0, 1, k2), 0, 0, rb0, );
        PHASE(READ_B(1, 1, rb1),               STAGE(As, srcA, 1, 0, k3), 0, 1, rb1, );
        PHASE(READ_A(1, 1),                    STAGE(Bs, srcB, 1, 0, k3), 1, 1, rb1, );
        PHASE(,                                STAGE(Bs, srcB, 1, 1, k3), 1, 0, rb0,
              asm volatile("s_waitcnt vmcnt(6)" ::: "memory"));
    }

    // Epilogue: D mapping col = lane&15, row = lq*4 + j within each 16x16 frag.
    const float ws = wscale_p[0];
#pragma unroll
    for (int m = 0; m < 8; ++m) {
        const int row0 = brow + m * 32 + wr * 16 + lq * 4;
#pragma unroll
        for (int j = 0; j < 4; ++j) {
            const int row = row0 + j;
            const float sc = scales[row] * ws;
#pragma unroll
            for (int n = 0; n < 4; ++n) {
                const int col = bcol + n * 64 + wc * 16 + l16;
                out[(size_t)row * OUT_F + col] = (float)acc[m][n][j] * sc + bias[col];
            }
        }
    }
#undef STAGE
#undef READ_A
#undef READ_B
#undef PHASE
}

extern "C" void kernel_launch(void* const* d_in, const int* in_sizes, int n_in,
                              void* d_out, int out_size, void* d_ws, size_t ws_size,
                              hipStream_t stream) {
    const float* x       = (const float*)d_in[0];
    const float* w_t     = (const float*)d_in[1];
    const float* w_scale = (const float*)d_in[2];
    const float* bias    = (const float*)d_in[3];
    float* out = (float*)d_out;

    int8_t* xq     = (int8_t*)d_ws;
    float*  scales = (float*)((char*)d_ws + (size_t)T_ROWS * IN_F);
    int8_t* w8     = (int8_t*)((char*)d_ws + (size_t)T_ROWS * IN_F + T_ROWS * sizeof(float));

    prep_kernel<<<T_ROWS + (OUT_F * IN_F) / (16 * 256), 256, 0, stream>>>(
        x, xq, scales, w_t, w8);

    gemm_kernel<<<(T_ROWS / 256) * (OUT_F / 256), 512, 0, stream>>>(
        xq, w8, scales, bias, w_scale, out);
}